// Round 1
// baseline (125.309 us; speedup 1.0000x reference)
//
#include <hip/hip_runtime.h>
#include <stdint.h>

#define GN 4008      // reference GRID
#define OWS 128      // occ words per row (126 used, padded)
#define CH 24        // vertical chunks
#define RPC 167      // rows per chunk; CH*RPC == GN exactly

static_assert(CH * RPC == GN, "chunking must cover grid exactly");

// ---------------- K1: build sparse corner-delta points from gt boxes -------
// JAX scatter semantics: negative index wraps (+GN), still-OOB update dropped.
// Invalid points encoded with px field = 4095 (never matches px <= x <= 4007).
__global__ void k_points(const float* __restrict__ gt, int ngt,
                         uint32_t* __restrict__ pts, double* __restrict__ acc) {
    int i = blockIdx.x * blockDim.x + threadIdx.x;
    if (i == 0) *acc = 0.0;
    if (i >= ngt) return;
    float4 b = ((const float4*)gt)[i];
    int x1 = (int)rintf(b.x * 100.0f);
    int y1 = (int)rintf(b.y * 100.0f);
    int x2 = (int)rintf(b.z * 100.0f);
    int y2 = (int)rintf(b.w * 100.0f);
    int xs[4] = {x1, x1, x2 + 1, x2 + 1};
    int ys[4] = {y1, y2 + 1, y1, y2 + 1};
    uint32_t sg[4] = {1u, 0u, 0u, 1u};   // +1, -1, -1, +1
    #pragma unroll
    for (int c = 0; c < 4; ++c) {
        int x = xs[c], y = ys[c];
        if (x < 0) x += GN;
        if (y < 0) y += GN;
        uint32_t v;
        if (x >= 0 && x < GN && y >= 0 && y < GN)
            v = ((uint32_t)x << 20) | ((uint32_t)y << 8) | sg[c];
        else
            v = 0xFFFFFFFFu;
        pts[i * 4 + c] = v;
    }
}

// ---------------- K2: per-row occ bitmap ----------------------------------
// Row x: build cumsumX(D)[x,:] in LDS from points with px<=x, horizontal
// inclusive scan -> full2d -> occ bit (>0), write bit-packed row.
__global__ __launch_bounds__(256) void k_occrow(const uint32_t* __restrict__ pts,
                                                int npts,
                                                uint32_t* __restrict__ occw) {
    __shared__ int row[4096];
    __shared__ int wsum[4];
    __shared__ uint16_t masks[256];
    int x = blockIdx.x;
    int t = threadIdx.x;
    for (int i = t; i < 4096; i += 256) row[i] = 0;
    __syncthreads();
    for (int i = t; i < npts; i += 256) {
        uint32_t p = pts[i];
        int px = (int)(p >> 20);
        if (px <= x) {
            int py = (int)((p >> 8) & 0xFFFu);
            atomicAdd(&row[py], (p & 1u) ? 1 : -1);
        }
    }
    __syncthreads();
    int base = t * 16;
    int v[16];
    int s = 0;
    #pragma unroll
    for (int j = 0; j < 16; ++j) { s += row[base + j]; v[j] = s; }
    // block scan of per-thread totals
    int lane = t & 63, wid = t >> 6;
    int ss = s;
    #pragma unroll
    for (int d = 1; d < 64; d <<= 1) {
        int tmp = __shfl_up(ss, d);
        if (lane >= d) ss += tmp;
    }
    if (lane == 63) wsum[wid] = ss;
    __syncthreads();
    int carry = ss - s;
    #pragma unroll
    for (int w = 0; w < 4; ++w) if (w < wid) carry += wsum[w];
    uint32_t m = 0;
    #pragma unroll
    for (int j = 0; j < 16; ++j) {
        int y = base + j;
        if (y < GN && (carry + v[j]) > 0) m |= (1u << j);
    }
    masks[t] = (uint16_t)m;
    __syncthreads();
    if (t < OWS) {
        uint32_t w0 = masks[2 * t];
        uint32_t w1 = masks[2 * t + 1];
        occw[(size_t)x * OWS + t] = w0 | (w1 << 16);
    }
}

// ---------------- K3: vertical chunk sums of occ bits ---------------------
__global__ void k_vsum(const uint32_t* __restrict__ occw, int* __restrict__ part) {
    int y = blockIdx.x * blockDim.x + threadIdx.x;
    int c = blockIdx.y;
    if (y >= GN) return;
    int w = y >> 5, b = y & 31;
    int x0 = c * RPC;
    int s = 0;
    #pragma unroll 4
    for (int i = 0; i < RPC; ++i) {
        uint32_t word = occw[(size_t)(x0 + i) * OWS + w];
        s += (int)((word >> b) & 1u);
    }
    part[c * GN + y] = s;
}

// ---------------- K4: exclusive scan of chunk sums per column -------------
__global__ void k_vscan(int* __restrict__ part) {
    int y = blockIdx.x * blockDim.x + threadIdx.x;
    if (y >= GN) return;
    int run = 0;
    #pragma unroll
    for (int c = 0; c < CH; ++c) {
        int t = part[c * GN + y];
        part[c * GN + y] = run;
        run += t;
    }
}

// ---------------- K5: emit vocc = cumsumX(occ) as int32 -------------------
__global__ void k_vocc(const uint32_t* __restrict__ occw, const int* __restrict__ part,
                       int* __restrict__ vocc) {
    int y = blockIdx.x * blockDim.x + threadIdx.x;
    int c = blockIdx.y;
    if (y >= GN) return;
    int w = y >> 5, b = y & 31;
    int x0 = c * RPC;
    int carry = part[c * GN + y];
    #pragma unroll 4
    for (int i = 0; i < RPC; ++i) {
        uint32_t word = occw[(size_t)(x0 + i) * OWS + w];
        carry += (int)((word >> b) & 1u);
        vocc[(size_t)(x0 + i) * GN + y] = carry;
    }
}

// ---------------- K6: in-place horizontal scan -> S (integral image) ------
__global__ __launch_bounds__(256) void k_hscan(int* __restrict__ vocc) {
    __shared__ int wsum[4];
    int x = blockIdx.x, t = threadIdx.x;
    size_t rb = (size_t)x * GN;
    int base = t * 16;
    int v[16];
    int s = 0;
    bool full = (base + 16 <= GN);
    if (full) {
        const int4* p = (const int4*)(vocc + rb + base);
        #pragma unroll
        for (int q = 0; q < 4; ++q) {
            int4 a = p[q];
            s += a.x; v[4 * q + 0] = s;
            s += a.y; v[4 * q + 1] = s;
            s += a.z; v[4 * q + 2] = s;
            s += a.w; v[4 * q + 3] = s;
        }
    } else {
        #pragma unroll
        for (int j = 0; j < 16; ++j) {
            int y = base + j;
            int val = (y < GN) ? vocc[rb + y] : 0;
            s += val; v[j] = s;
        }
    }
    int lane = t & 63, wid = t >> 6;
    int ss = s;
    #pragma unroll
    for (int d = 1; d < 64; d <<= 1) {
        int tmp = __shfl_up(ss, d);
        if (lane >= d) ss += tmp;
    }
    if (lane == 63) wsum[wid] = ss;
    __syncthreads();
    int carry = ss - s;
    #pragma unroll
    for (int w = 0; w < 4; ++w) if (w < wid) carry += wsum[w];
    if (full) {
        int4* p = (int4*)(vocc + rb + base);
        #pragma unroll
        for (int q = 0; q < 4; ++q)
            p[q] = make_int4(v[4 * q + 0] + carry, v[4 * q + 1] + carry,
                             v[4 * q + 2] + carry, v[4 * q + 3] + carry);
    } else {
        #pragma unroll
        for (int j = 0; j < 16; ++j) {
            int y = base + j;
            if (y < GN) vocc[rb + y] = v[j] + carry;
        }
    }
}

// ---------------- K7: gather + reduce -------------------------------------
__device__ __forceinline__ int clampI(int a) {
    return a < 0 ? 0 : (a > GN ? GN : a);
}

__global__ __launch_bounds__(256) void k_gather(const float* __restrict__ pred, int npred,
                                                const int* __restrict__ S,
                                                double* __restrict__ acc) {
    __shared__ double red[4];
    int i = blockIdx.x * blockDim.x + threadIdx.x;
    double l = 0.0;
    if (i < npred) {
        float4 b = ((const float4*)pred)[i];
        int x1 = (int)rintf(b.x * 100.0f);
        int y1 = (int)rintf(b.y * 100.0f);
        int x2 = (int)rintf(b.z * 100.0f);
        int y2 = (int)rintf(b.w * 100.0f);
        int a1 = clampI(x1), b1 = clampI(y1), a2 = clampI(x2), b2 = clampI(y2);
        // I[a,b] of padded integral image: 0 on first row/col, else S[a-1,b-1]
        int i22 = (a2 && b2) ? S[(size_t)(a2 - 1) * GN + (b2 - 1)] : 0;
        int i12 = (a1 && b2) ? S[(size_t)(a1 - 1) * GN + (b2 - 1)] : 0;
        int i21 = (a2 && b1) ? S[(size_t)(a2 - 1) * GN + (b1 - 1)] : 0;
        int i11 = (a1 && b1) ? S[(size_t)(a1 - 1) * GN + (b1 - 1)] : 0;
        int cov = i22 - i12 - i21 + i11;
        int area = (x2 - x1) * (y2 - y1);
        bool valid = (x2 > x1) && (y2 > y1);
        float iou = valid ? ((float)cov / fmaxf((float)area, 1.0f)) : 0.0f;
        l = (double)(1.0f - iou);
    }
    #pragma unroll
    for (int d = 32; d > 0; d >>= 1) l += __shfl_down(l, d);
    int lane = threadIdx.x & 63, wid = threadIdx.x >> 6;
    if (lane == 0) red[wid] = l;
    __syncthreads();
    if (threadIdx.x == 0) {
        atomicAdd(acc, red[0] + red[1] + red[2] + red[3]);
    }
}

// ---------------- K8: finalize --------------------------------------------
__global__ void k_final(const double* __restrict__ acc, float* __restrict__ out, int npred) {
    out[0] = (float)(*acc / (double)npred);
}

extern "C" void kernel_launch(void* const* d_in, const int* in_sizes, int n_in,
                              void* d_out, int out_size, void* d_ws, size_t ws_size,
                              hipStream_t stream) {
    const float* pred = (const float*)d_in[0];
    // d_in[1] = target, unused by the reference loss
    const float* gt = (const float*)d_in[2];
    int npred = in_sizes[0] / 4;
    int ngt = in_sizes[2] / 4;
    int npts = ngt * 4;

    char* ws = (char*)d_ws;
    size_t off = 0;
    int* vocc = (int*)(ws + off);          off += (size_t)GN * GN * sizeof(int);      // 64.3 MB, later holds S
    uint32_t* occw = (uint32_t*)(ws + off); off += (size_t)GN * OWS * sizeof(uint32_t); // 2.05 MB
    int* part = (int*)(ws + off);          off += (size_t)CH * GN * sizeof(int);      // 385 KB
    uint32_t* pts = (uint32_t*)(ws + off); off += (size_t)npts * sizeof(uint32_t);
    off = (off + 15) & ~(size_t)15;
    double* acc = (double*)(ws + off);

    dim3 blk(256);
    k_points<<<dim3((ngt + 255) / 256), blk, 0, stream>>>(gt, ngt, pts, acc);
    k_occrow<<<dim3(GN), blk, 0, stream>>>(pts, npts, occw);
    dim3 gv((GN + 255) / 256, CH);
    k_vsum<<<gv, blk, 0, stream>>>(occw, part);
    k_vscan<<<dim3((GN + 255) / 256), blk, 0, stream>>>(part);
    k_vocc<<<gv, blk, 0, stream>>>(occw, part, vocc);
    k_hscan<<<dim3(GN), blk, 0, stream>>>(vocc);
    k_gather<<<dim3((npred + 255) / 256), blk, 0, stream>>>(pred, npred, vocc, acc);
    k_final<<<1, 1, 0, stream>>>(acc, (float*)d_out, npred);
}

// Round 2
// 98.058 us; speedup vs baseline: 1.2779x; 1.2779x over previous
//
#include <hip/hip_runtime.h>
#include <stdint.h>

#define GN 4008      // reference GRID
#define OWS 128      // occ words per row (126 used, padded)
#define PW 128       // P16 words per row
#define CH 167       // vertical chunks
#define RPC 24       // rows per chunk; CH*RPC == GN exactly
#define CPAD 4096    // padded column dim for chunk-level arrays
#define RPADN 4352   // padded LDS running-row size (fpad(4095)=4350)

static_assert(CH * RPC == GN, "chunking must cover grid exactly");

__device__ __forceinline__ int fpad(int y) { return y + (y >> 4); }

// ---------------- K1: sparse corner-delta points from gt boxes -------------
// JAX scatter semantics: negative index wraps (+GN), still-OOB update dropped.
// Invalid points encoded with px field = 4095 (outside every chunk range).
__global__ void k_points(const float* __restrict__ gt, int ngt,
                         uint32_t* __restrict__ pts, double* __restrict__ acc) {
    int i = blockIdx.x * blockDim.x + threadIdx.x;
    if (i == 0) *acc = 0.0;
    if (i >= ngt) return;
    float4 b = ((const float4*)gt)[i];
    int x1 = (int)rintf(b.x * 100.0f);
    int y1 = (int)rintf(b.y * 100.0f);
    int x2 = (int)rintf(b.z * 100.0f);
    int y2 = (int)rintf(b.w * 100.0f);
    int xs[4] = {x1, x1, x2 + 1, x2 + 1};
    int ys[4] = {y1, y2 + 1, y1, y2 + 1};
    uint32_t sg[4] = {1u, 0u, 0u, 1u};   // +1, -1, -1, +1
    #pragma unroll
    for (int c = 0; c < 4; ++c) {
        int x = xs[c], y = ys[c];
        if (x < 0) x += GN;
        if (y < 0) y += GN;
        uint32_t v;
        if (x >= 0 && x < GN && y >= 0 && y < GN)
            v = ((uint32_t)x << 20) | ((uint32_t)y << 8) | sg[c];
        else
            v = 0xFFFFFFFFu;
        pts[i * 4 + c] = v;
    }
}

// ---------------- K2: chunked incremental occ build ------------------------
// Block c owns rows [c*RPC, (c+1)*RPC). Keeps R[y] = cumsum_x D[.][y] in LDS
// (padded stride 17 per 16 to avoid bank conflicts). Emits per row: bit-packed
// occ words + P16 (row word-popcount exclusive prefix). Accumulates per-column
// bit counts -> colsum[c][y] (u16, packed as u32 pairs).
__global__ __launch_bounds__(256) void k_occ2(const uint32_t* __restrict__ pts, int npts,
                                              uint32_t* __restrict__ occw,
                                              uint16_t* __restrict__ P16,
                                              uint32_t* __restrict__ colsum32) {
    __shared__ int R[RPADN];
    __shared__ uint32_t loc[8192];
    __shared__ int nloc;
    __shared__ uint16_t masks[256];
    __shared__ int wsum[4];
    __shared__ int wtot[2];
    int c = blockIdx.x;
    int r0 = c * RPC;
    int t = threadIdx.x;
    for (int i = t; i < RPADN; i += 256) R[i] = 0;
    if (t == 0) nloc = 0;
    __syncthreads();
    // seed with all points before this chunk; collect in-chunk points to LDS
    for (int i = t; i < npts; i += 256) {
        uint32_t p = pts[i];
        int px = (int)(p >> 20);
        if (px < r0) {
            atomicAdd(&R[fpad((int)((p >> 8) & 0xFFFu))], (p & 1u) ? 1 : -1);
        } else if (px < r0 + RPC) {
            int k = atomicAdd(&nloc, 1);
            loc[k] = p;
        }
    }
    __syncthreads();
    int nl = nloc;
    uint32_t cnt[16];
    #pragma unroll
    for (int j = 0; j < 16; ++j) cnt[j] = 0;
    int lane = t & 63, wid = t >> 6;
    int base = t * 16, pb = 17 * t;
    for (int xr = 0; xr < RPC; ++xr) {
        int x = r0 + xr;
        for (int i = t; i < nl; i += 256) {
            uint32_t p = loc[i];
            if ((int)(p >> 20) == x)
                atomicAdd(&R[fpad((int)((p >> 8) & 0xFFFu))], (p & 1u) ? 1 : -1);
        }
        __syncthreads();                       // A: deltas visible
        int v[16], s = 0;
        #pragma unroll
        for (int j = 0; j < 16; ++j) { s += R[pb + j]; v[j] = s; }
        int ss = s;
        #pragma unroll
        for (int d = 1; d < 64; d <<= 1) {
            int tmp = __shfl_up(ss, d);
            if (lane >= d) ss += tmp;
        }
        if (lane == 63) wsum[wid] = ss;
        __syncthreads();                       // B: wsum visible, R reads done
        int carry = ss - s;
        #pragma unroll
        for (int w = 0; w < 4; ++w) if (w < wid) carry += wsum[w];
        uint32_t m = 0;
        #pragma unroll
        for (int j = 0; j < 16; ++j) {
            int y = base + j;
            if (y < GN && (carry + v[j]) > 0) m |= (1u << j);
        }
        #pragma unroll
        for (int j = 0; j < 16; ++j) cnt[j] += (m >> j) & 1u;
        masks[t] = (uint16_t)m;
        __syncthreads();                       // C: masks visible
        uint32_t word = 0; int pop = 0;
        if (t < 128) {
            word = (uint32_t)masks[2 * t] | ((uint32_t)masks[2 * t + 1] << 16);
            pop = __popc(word);
        }
        int ps = pop;
        #pragma unroll
        for (int d = 1; d < 64; d <<= 1) {
            int tmp = __shfl_up(ps, d);
            if (lane >= d) ps += tmp;
        }
        if (lane == 63 && wid < 2) wtot[wid] = ps;
        __syncthreads();                       // D: wtot visible
        if (t < 128) {
            int excl = ps - pop + (wid == 1 ? wtot[0] : 0);
            P16[(size_t)x * PW + t] = (uint16_t)excl;
            occw[(size_t)x * OWS + t] = word;
        }
        __syncthreads();                       // E: protect masks/wsum reuse
    }
    uint32_t* cs = colsum32 + ((size_t)c * CPAD) / 2 + (size_t)t * 8;
    #pragma unroll
    for (int q = 0; q < 8; ++q)
        cs[q] = cnt[2 * q] | (cnt[2 * q + 1] << 16);
}

// ---------------- K3: vertical exclusive scan of chunk colsums -------------
// Vc[c][y] = bits at column y in rows < c*RPC, c in [0, CH]. u16 (max 4008).
__global__ __launch_bounds__(256) void k_vscanc(const uint16_t* __restrict__ colsum,
                                                uint16_t* __restrict__ Vc) {
    int y = blockIdx.x * 256 + threadIdx.x;    // 16*256 == CPAD
    uint32_t run = 0;
    Vc[y] = 0;
    int c = 0;
    for (; c + 8 <= CH; c += 8) {
        uint16_t a0 = colsum[(size_t)(c + 0) * CPAD + y];
        uint16_t a1 = colsum[(size_t)(c + 1) * CPAD + y];
        uint16_t a2 = colsum[(size_t)(c + 2) * CPAD + y];
        uint16_t a3 = colsum[(size_t)(c + 3) * CPAD + y];
        uint16_t a4 = colsum[(size_t)(c + 4) * CPAD + y];
        uint16_t a5 = colsum[(size_t)(c + 5) * CPAD + y];
        uint16_t a6 = colsum[(size_t)(c + 6) * CPAD + y];
        uint16_t a7 = colsum[(size_t)(c + 7) * CPAD + y];
        run += a0; Vc[(size_t)(c + 1) * CPAD + y] = (uint16_t)run;
        run += a1; Vc[(size_t)(c + 2) * CPAD + y] = (uint16_t)run;
        run += a2; Vc[(size_t)(c + 3) * CPAD + y] = (uint16_t)run;
        run += a3; Vc[(size_t)(c + 4) * CPAD + y] = (uint16_t)run;
        run += a4; Vc[(size_t)(c + 5) * CPAD + y] = (uint16_t)run;
        run += a5; Vc[(size_t)(c + 6) * CPAD + y] = (uint16_t)run;
        run += a6; Vc[(size_t)(c + 7) * CPAD + y] = (uint16_t)run;
        run += a7; Vc[(size_t)(c + 8) * CPAD + y] = (uint16_t)run;
    }
    for (; c < CH; ++c) {
        run += colsum[(size_t)c * CPAD + y];
        Vc[(size_t)(c + 1) * CPAD + y] = (uint16_t)run;
    }
}

// ---------------- K4: horizontal inclusive scan of Vc rows -> Ic -----------
// Ic[c][y] = bits in rows < c*RPC, cols <= y. i32 (max 16M).
__global__ __launch_bounds__(256) void k_hscanc(const uint16_t* __restrict__ Vc,
                                                int* __restrict__ Ic) {
    __shared__ int wsum[4];
    int c = blockIdx.x, t = threadIdx.x;
    const uint32_t* row = (const uint32_t*)(Vc + (size_t)c * CPAD);
    const int4* p = (const int4*)(row + (size_t)t * 8);
    int4 A = p[0];
    int4 B = p[1];
    uint32_t w[8] = {(uint32_t)A.x, (uint32_t)A.y, (uint32_t)A.z, (uint32_t)A.w,
                     (uint32_t)B.x, (uint32_t)B.y, (uint32_t)B.z, (uint32_t)B.w};
    int v[16], s = 0;
    #pragma unroll
    for (int q = 0; q < 8; ++q) {
        s += (int)(w[q] & 0xFFFFu); v[2 * q] = s;
        s += (int)(w[q] >> 16);     v[2 * q + 1] = s;
    }
    int lane = t & 63, wid = t >> 6;
    int ss = s;
    #pragma unroll
    for (int d = 1; d < 64; d <<= 1) {
        int tmp = __shfl_up(ss, d);
        if (lane >= d) ss += tmp;
    }
    if (lane == 63) wsum[wid] = ss;
    __syncthreads();
    int carry = ss - s;
    #pragma unroll
    for (int w2 = 0; w2 < 4; ++w2) if (w2 < wid) carry += wsum[w2];
    int4* o = (int4*)(Ic + (size_t)c * CPAD + (size_t)t * 16);
    #pragma unroll
    for (int q = 0; q < 4; ++q)
        o[q] = make_int4(v[4 * q + 0] + carry, v[4 * q + 1] + carry,
                         v[4 * q + 2] + carry, v[4 * q + 3] + carry);
}

// ---------------- K5: gather + reduce --------------------------------------
__device__ __forceinline__ int clampI(int a) {
    return a < 0 ? 0 : (a > GN ? GN : a);
}

// I(a,b) = # occ bits in rows < a, cols < b  (padded integral image value)
__device__ __forceinline__ int Ifun(int a, int b,
                                    const int* __restrict__ Ic,
                                    const uint16_t* __restrict__ P16,
                                    const uint32_t* __restrict__ occw) {
    if (a <= 0 || b <= 0) return 0;
    int c = a / RPC;
    int s = Ic[(size_t)c * CPAD + (b - 1)];
    int bw = b >> 5;
    uint32_t mask = (1u << (b & 31)) - 1u;   // b&31==0 -> 0
    for (int x = c * RPC; x < a; ++x)
        s += (int)P16[(size_t)x * PW + bw] + __popc(occw[(size_t)x * OWS + bw] & mask);
    return s;
}

__global__ __launch_bounds__(256) void k_gather(const float* __restrict__ pred, int npred,
                                                const int* __restrict__ Ic,
                                                const uint16_t* __restrict__ P16,
                                                const uint32_t* __restrict__ occw,
                                                double* __restrict__ acc) {
    __shared__ double red[4];
    int i = blockIdx.x * blockDim.x + threadIdx.x;
    double l = 0.0;
    if (i < npred) {
        float4 b = ((const float4*)pred)[i];
        int x1 = (int)rintf(b.x * 100.0f);
        int y1 = (int)rintf(b.y * 100.0f);
        int x2 = (int)rintf(b.z * 100.0f);
        int y2 = (int)rintf(b.w * 100.0f);
        int a1 = clampI(x1), b1 = clampI(y1), a2 = clampI(x2), b2 = clampI(y2);
        int cov = Ifun(a2, b2, Ic, P16, occw) - Ifun(a1, b2, Ic, P16, occw)
                - Ifun(a2, b1, Ic, P16, occw) + Ifun(a1, b1, Ic, P16, occw);
        int area = (x2 - x1) * (y2 - y1);
        bool valid = (x2 > x1) && (y2 > y1);
        float iou = valid ? ((float)cov / fmaxf((float)area, 1.0f)) : 0.0f;
        l = (double)(1.0f - iou);
    }
    #pragma unroll
    for (int d = 32; d > 0; d >>= 1) l += __shfl_down(l, d);
    int lane = threadIdx.x & 63, wid = threadIdx.x >> 6;
    if (lane == 0) red[wid] = l;
    __syncthreads();
    if (threadIdx.x == 0) {
        atomicAdd(acc, red[0] + red[1] + red[2] + red[3]);
    }
}

// ---------------- K6: finalize ---------------------------------------------
__global__ void k_final(const double* __restrict__ acc, float* __restrict__ out, int npred) {
    out[0] = (float)(*acc / (double)npred);
}

extern "C" void kernel_launch(void* const* d_in, const int* in_sizes, int n_in,
                              void* d_out, int out_size, void* d_ws, size_t ws_size,
                              hipStream_t stream) {
    const float* pred = (const float*)d_in[0];
    // d_in[1] = target, unused by the reference loss
    const float* gt = (const float*)d_in[2];
    int npred = in_sizes[0] / 4;
    int ngt = in_sizes[2] / 4;
    int npts = ngt * 4;

    char* ws = (char*)d_ws;
    size_t off = 0;
    auto alloc = [&](size_t bytes) {
        void* p = ws + off;
        off = (off + bytes + 255) & ~(size_t)255;
        return p;
    };
    uint32_t* occw = (uint32_t*)alloc((size_t)GN * OWS * sizeof(uint32_t));   // 2.05 MB
    int* Ic = (int*)alloc((size_t)(CH + 1) * CPAD * sizeof(int));             // 2.75 MB
    uint16_t* P16 = (uint16_t*)alloc((size_t)GN * PW * sizeof(uint16_t));     // 1.03 MB
    uint16_t* colsum = (uint16_t*)alloc((size_t)CH * CPAD * sizeof(uint16_t)); // 1.37 MB
    uint16_t* Vc = (uint16_t*)alloc((size_t)(CH + 1) * CPAD * sizeof(uint16_t)); // 1.38 MB
    uint32_t* pts = (uint32_t*)alloc((size_t)npts * sizeof(uint32_t));
    double* acc = (double*)alloc(sizeof(double));

    dim3 blk(256);
    k_points<<<dim3((ngt + 255) / 256), blk, 0, stream>>>(gt, ngt, pts, acc);
    k_occ2<<<dim3(CH), blk, 0, stream>>>(pts, npts, occw, P16, (uint32_t*)colsum);
    k_vscanc<<<dim3(CPAD / 256), blk, 0, stream>>>(colsum, Vc);
    k_hscanc<<<dim3(CH + 1), blk, 0, stream>>>(Vc, Ic);
    k_gather<<<dim3((npred + 255) / 256), blk, 0, stream>>>(pred, npred, Ic, P16, occw, acc);
    k_final<<<1, 1, 0, stream>>>(acc, (float*)d_out, npred);
}